// Round 13
// baseline (385.232 us; speedup 1.0000x reference)
//
#include <hip/hip_runtime.h>
#include <hip/hip_bf16.h>

// GCN, CSR-gather, bf16 T-tables, fused agg+matvec (round-11 agg_mm),
// 3-pass binned CSR build (block-exclusive writes, no cross-XCD line sharing):
//   binA: edges -> 8 windows (d>>13), staging1 u32 = (d&8191)<<16 | src
//   binB: window -> 256 sub-buckets (d>>5, 32 nodes), staging2 u32 = (d&31)<<16 | src
//   bucket_degB/fillC: one block per bucket, LDS cursors, exclusive csr region.

__device__ __forceinline__ unsigned f2bf(float f) {   // round-to-nearest-even
    unsigned u = __float_as_uint(f);
    return (u + 0x7FFFu + ((u >> 16) & 1u)) >> 16;
}
__device__ __forceinline__ float bflo(unsigned w) { return __uint_as_float(w << 16); }
__device__ __forceinline__ float bfhi(unsigned w) { return __uint_as_float(w & 0xFFFF0000u); }

// ---- pass A: bin by window w = d>>13 ----
__global__ __launch_bounds__(256) void binA(
        const int* __restrict__ src, const int* __restrict__ dst,
        int* __restrict__ gcur1, unsigned* __restrict__ st1,
        int E, int cap1) {
    __shared__ unsigned buf[2048];
    __shared__ int hist[8], base[8], pos[8];
    int t = threadIdx.x;
    int beg = blockIdx.x * 2048;
    int end = min(beg + 2048, E);
    if (t < 8) hist[t] = 0;
    __syncthreads();
    for (int i = beg + t; i < end; i += 256)
        atomicAdd(&hist[dst[i] >> 13], 1);
    __syncthreads();
    if (t == 0) {
        int acc = 0;
        for (int w = 0; w < 8; ++w) { base[w] = acc; pos[w] = acc; acc += hist[w]; }
    }
    __syncthreads();
    for (int i = beg + t; i < end; i += 256) {
        int d = dst[i];
        int p = atomicAdd(&pos[d >> 13], 1);
        buf[p] = ((unsigned)(d & 8191) << 16) | (unsigned)src[i];
    }
    __syncthreads();
    int wave = t >> 6, lane = t & 63;
    for (int w = wave; w < 8; w += 4) {
        int lo = base[w], cnt = pos[w] - lo;
        if (cnt == 0) continue;
        int g;
        if (lane == 0) g = atomicAdd(&gcur1[w], cnt);
        g = __shfl(g, 0, 64);
        unsigned* out = st1 + (size_t)w * cap1 + g;
        for (int k = lane; k < cnt; k += 64) out[k] = buf[lo + k];
    }
}

// ---- pass B: refine window into 256 sub-buckets (32 nodes each) ----
#define CSLOT 68
__global__ __launch_bounds__(256) void binB(
        const int* __restrict__ gcur1, const unsigned* __restrict__ st1,
        int* __restrict__ gcur2, unsigned* __restrict__ st2,
        int cap1, int cap2) {
    __shared__ unsigned buf[4096];
    __shared__ int hist[256], base[256], pos[256];
    int t = threadIdx.x;
    int w = blockIdx.x / CSLOT, c = blockIdx.x % CSLOT;
    int cnt1 = gcur1[w];
    int beg = c * 4096;
    int end = min(beg + 4096, cnt1);
    if (beg >= end) return;                 // block-uniform
    int bulkBase = w * 256;                 // first bucket of this window
    hist[t] = 0;
    __syncthreads();
    const unsigned* in = st1 + (size_t)w * cap1;
    for (int i = beg + t; i < end; i += 256) {
        int dL = (int)(in[i] >> 16);        // d & 8191
        atomicAdd(&hist[dL >> 5], 1);
    }
    __syncthreads();
    int v = hist[t];
    base[t] = v;
    __syncthreads();
    for (int o = 1; o < 256; o <<= 1) {
        int u = (t >= o) ? base[t - o] : 0;
        __syncthreads();
        base[t] += u;
        __syncthreads();
    }
    int excl = base[t] - v;
    __syncthreads();
    base[t] = excl; pos[t] = excl;
    __syncthreads();
    for (int i = beg + t; i < end; i += 256) {
        unsigned e = in[i];
        int dL = (int)(e >> 16);
        int p = atomicAdd(&pos[dL >> 5], 1);
        buf[p] = ((unsigned)(dL & 31) << 16) | (e & 0xFFFFu);
    }
    __syncthreads();
    int wave = t >> 6, lane = t & 63;
    for (int gl = wave; gl < 256; gl += 4) {
        int lo = base[gl], cnt = pos[gl] - lo;
        if (cnt == 0) continue;
        int g0;
        if (lane == 0) g0 = atomicAdd(&gcur2[bulkBase + gl], cnt);
        g0 = __shfl(g0, 0, 64);
        unsigned* out = st2 + (size_t)(bulkBase + gl) * cap2 + g0;
        for (int k = lane; k < cnt; k += 64) out[k] = buf[lo + k];
    }
}

// ---- degree per bucket (block-exclusive) ----
__global__ __launch_bounds__(256) void bucket_degB(
        const int* __restrict__ gcur2, const unsigned* __restrict__ st2,
        int* __restrict__ degi, int n, int cap2) {
    __shared__ int h[32];
    int g = blockIdx.x, t = threadIdx.x;
    int gLo = g << 5;
    int nb = min(32, n - gLo);
    if (t < 32) h[t] = 0;
    __syncthreads();
    int cnt = gcur2[g];
    const unsigned* in = st2 + (size_t)g * cap2;
    for (int i = t; i < cnt; i += 256) atomicAdd(&h[in[i] >> 16], 1);
    __syncthreads();
    if (t < nb) degi[gLo + t] = h[t];
}

__global__ void scan_part(const int* __restrict__ degi, int* __restrict__ part, int n) {
    __shared__ int ls[256];
    int i = blockIdx.x * 256 + threadIdx.x;
    ls[threadIdx.x] = (i < n) ? degi[i] : 0;
    __syncthreads();
    for (int o = 128; o > 0; o >>= 1) {
        if (threadIdx.x < o) ls[threadIdx.x] += ls[threadIdx.x + o];
        __syncthreads();
    }
    if (threadIdx.x == 0) part[blockIdx.x] = ls[0];
}

__global__ void scan_root(int* __restrict__ part, int nblk) {   // nblk <= 256
    __shared__ int ls[256];
    int t = threadIdx.x;
    int v = (t < nblk) ? part[t] : 0;
    ls[t] = v;
    __syncthreads();
    for (int o = 1; o < 256; o <<= 1) {
        int u = (t >= o) ? ls[t - o] : 0;
        __syncthreads();
        ls[t] += u;
        __syncthreads();
    }
    if (t < nblk) part[t] = ls[t] - v;   // exclusive
}

__global__ void scan_write(const int* __restrict__ degi, const int* __restrict__ part,
                           int* __restrict__ off, float* __restrict__ dinv, int n) {
    __shared__ int ls[256];
    int t = threadIdx.x, i = blockIdx.x * 256 + t;
    int d = (i < n) ? degi[i] : 0;
    ls[t] = d;
    __syncthreads();
    for (int o = 1; o < 256; o <<= 1) {
        int u = (t >= o) ? ls[t - o] : 0;
        __syncthreads();
        ls[t] += u;
        __syncthreads();
    }
    if (i < n) {
        int o0 = part[blockIdx.x] + ls[t] - d;
        off[i] = o0;
        dinv[i] = rsqrtf((float)d + 1.0f);   // +1 self loop
        if (i == n - 1) off[n] = o0 + d;
    }
}

// ---- fill csr: one block per bucket, LDS cursors, exclusive region ----
__global__ __launch_bounds__(256) void fillC(
        const int* __restrict__ gcur2, const unsigned* __restrict__ st2,
        const int* __restrict__ off, int* __restrict__ csr, int n, int cap2) {
    __shared__ int cur[32];
    int g = blockIdx.x, t = threadIdx.x;
    int gLo = g << 5;
    int nb = min(32, n - gLo);
    if (t < nb) cur[t] = off[gLo + t];
    __syncthreads();
    int cnt = gcur2[g];
    const unsigned* in = st2 + (size_t)g * cap2;
    for (int i = t; i < cnt; i += 256) {
        unsigned e = in[i];
        int p = atomicAdd(&cur[e >> 16], 1);
        csr[p] = (int)(e & 0xFFFFu);
    }
}

// ---- T1 = bf16(x * dinv) ----
__global__ void prescale(const float* __restrict__ x, const float* __restrict__ dinv,
                         unsigned* __restrict__ T, int n) {
    int tid = blockIdx.x * blockDim.x + threadIdx.x;
    int stride = gridDim.x * blockDim.x;
    int total = n * 32;   // u32 count (2 features each)
    const float2* x2 = (const float2*)x;
    for (int i = tid; i < total; i += stride) {
        float2 v = x2[i];
        float dv = dinv[i >> 5];
        T[i] = f2bf(v.x * dv) | (f2bf(v.y * dv) << 16);
    }
}

// ---- T2 = bf16(relu(BN(y)) * dinv) ----
__global__ void bnrelu_scale(const float* __restrict__ Y, const double* __restrict__ stats,
                             const float* __restrict__ g, const float* __restrict__ bt,
                             const float* __restrict__ dinv, unsigned* __restrict__ T, int n) {
    int jj = threadIdx.x & 31;            // u32 index within row
    int f0 = jj * 2, f1 = jj * 2 + 1;
    double m0 = stats[f0] / n, m1 = stats[f1] / n;
    double v0 = stats[64 + f0] / n - m0 * m0, v1 = stats[64 + f1] / n - m1 * m1;
    float sc0 = (float)(1.0 / sqrt(v0 + 1e-5)) * g[f0];
    float sc1 = (float)(1.0 / sqrt(v1 + 1e-5)) * g[f1];
    float sh0 = bt[f0] - (float)m0 * sc0;
    float sh1 = bt[f1] - (float)m1 * sc1;
    const float2* Y2 = (const float2*)Y;
    int tid = blockIdx.x * blockDim.x + threadIdx.x;
    int stride = gridDim.x * blockDim.x;   // multiple of 32
    for (int i = tid; i < n * 32; i += stride) {
        float2 y = Y2[i];
        float dv = dinv[i >> 5];
        float a = fmaxf(y.x * sc0 + sh0, 0.f) * dv;
        float b = fmaxf(y.y * sc1 + sh1, 0.f) * dv;
        T[i] = f2bf(a) | (f2bf(b) << 16);
    }
}

// ---- fused layer: bf16 gather-sum (f32 accum) -> @W -> *dinv + b -> stats ----
__global__ __launch_bounds__(256) void agg_mm(
        const uint4* __restrict__ Tb, const int* __restrict__ csr,
        const int* __restrict__ off, const float* __restrict__ dinv,
        const float* __restrict__ W, const float* __restrict__ bias,
        double* __restrict__ stats_out, float* __restrict__ Y, int n) {
    __shared__ float Wl[64 * 64];
    __shared__ double ls[256], lq[256];
    for (int t = threadIdx.x; t < 64 * 64; t += blockDim.x) Wl[t] = W[t];

    int lane = threadIdx.x & 63;
    int slot = lane >> 3;      // 8 edge slots
    int fl   = lane & 7;       // features 8*fl .. 8*fl+7  (one uint4 = 8 bf16)
    float bv = bias[lane];
    __syncthreads();

    int wave  = (blockIdx.x * blockDim.x + threadIdx.x) >> 6;
    int nwave = (gridDim.x * blockDim.x) >> 6;
    double s = 0.0, sq = 0.0;

    for (int i = wave; i < n; i += nwave) {
        int beg = off[i], end = off[i + 1];
        float dv = dinv[i];

        float4 al = {0,0,0,0}, ah = {0,0,0,0};
        if (slot == 0) {                       // self term in slot 0 only
            uint4 r = Tb[(size_t)i * 8 + fl];
            al.x = bflo(r.x); al.y = bfhi(r.x);
            al.z = bflo(r.y); al.w = bfhi(r.y);
            ah.x = bflo(r.z); ah.y = bfhi(r.z);
            ah.z = bflo(r.w); ah.w = bfhi(r.w);
        }

        #pragma unroll 2
        for (int c = beg + slot; c < end; c += 8) {
            int sr = csr[c];                    // 8-lane broadcast per slot
            uint4 r = Tb[(size_t)sr * 8 + fl];
            al.x += bflo(r.x); al.y += bfhi(r.x);
            al.z += bflo(r.y); al.w += bfhi(r.y);
            ah.x += bflo(r.z); ah.y += bfhi(r.z);
            ah.z += bflo(r.w); ah.w += bfhi(r.w);
        }

        // reduce across the 8 slots (lane bits 3,4,5)
        #pragma unroll
        for (int m = 8; m <= 32; m <<= 1) {
            al.x += __shfl_xor(al.x, m, 64); al.y += __shfl_xor(al.y, m, 64);
            al.z += __shfl_xor(al.z, m, 64); al.w += __shfl_xor(al.w, m, 64);
            ah.x += __shfl_xor(ah.x, m, 64); ah.y += __shfl_xor(ah.y, m, 64);
            ah.z += __shfl_xor(ah.z, m, 64); ah.w += __shfl_xor(ah.w, m, 64);
        }

        // matvec: feature k owned by lane (k>>3), component (k&7)
        float acc = 0.f;
        #pragma unroll
        for (int k = 0; k < 64; ++k) {
            const int c = k & 7, sl = k >> 3;
            float comp = c == 0 ? al.x : c == 1 ? al.y : c == 2 ? al.z : c == 3 ? al.w
                       : c == 4 ? ah.x : c == 5 ? ah.y : c == 6 ? ah.z : ah.w;
            acc = fmaf(__shfl(comp, sl, 64), Wl[k * 64 + lane], acc);
        }
        float yv = dv * acc + bv;
        Y[(size_t)i * 64 + lane] = yv;
        s += (double)yv; sq += (double)yv * (double)yv;
    }

    ls[threadIdx.x] = s; lq[threadIdx.x] = sq;
    __syncthreads();
    if (threadIdx.x < 64) {
        double ts = ls[threadIdx.x] + ls[threadIdx.x + 64] + ls[threadIdx.x + 128] + ls[threadIdx.x + 192];
        double tq = lq[threadIdx.x] + lq[threadIdx.x + 64] + lq[threadIdx.x + 128] + lq[threadIdx.x + 192];
        atomicAdd(&stats_out[threadIdx.x], ts);
        atomicAdd(&stats_out[64 + threadIdx.x], tq);
    }
}

// ---- head: hs3[row] = (relu(BN(y2[row])) . W3) * dinv[row] ----
__global__ void head_w3(const float* __restrict__ Y, const double* __restrict__ stats,
                        const float* __restrict__ g, const float* __restrict__ bt,
                        const float* __restrict__ W3, const float* __restrict__ dinv,
                        float* __restrict__ hs3, int n) {
    int lane = threadIdx.x & 63;
    double mean = stats[lane] / n;
    double var  = stats[64 + lane] / n - mean * mean;
    float scale = (float)(1.0 / sqrt(var + 1e-5)) * g[lane];
    float shift = bt[lane] - (float)mean * scale;
    float w = W3[lane];
    int wave  = (blockIdx.x * blockDim.x + threadIdx.x) >> 6;
    int nwave = (gridDim.x * blockDim.x) >> 6;
    for (int row = wave; row < n; row += nwave) {
        float v = fmaxf(Y[(size_t)row * 64 + lane] * scale + shift, 0.f) * w;
        #pragma unroll
        for (int o = 32; o > 0; o >>= 1) v += __shfl_down(v, o, 64);
        if (lane == 0) hs3[row] = v * dinv[row];
    }
}

// ---- layer-3 aggregation: wave per node, lane-parallel edge gather ----
__global__ void agg1(const float* __restrict__ hs3, const int* __restrict__ csr,
                     const int* __restrict__ off, const float* __restrict__ dinv,
                     const float* __restrict__ b3, float* __restrict__ out, int n) {
    float b = b3[0];
    int lane  = threadIdx.x & 63;
    int wave  = (blockIdx.x * blockDim.x + threadIdx.x) >> 6;
    int nwave = (gridDim.x * blockDim.x) >> 6;
    for (int i = wave; i < n; i += nwave) {
        int beg = off[i], end = off[i + 1];
        float acc = 0.f;
        for (int e = beg + lane; e < end; e += 64) acc += hs3[csr[e]];
        #pragma unroll
        for (int o = 32; o > 0; o >>= 1) acc += __shfl_down(acc, o, 64);
        if (lane == 0) out[i] = dinv[i] * (acc + hs3[i]) + b;
    }
}

extern "C" void kernel_launch(void* const* d_in, const int* in_sizes, int n_in,
                              void* d_out, int out_size, void* d_ws, size_t ws_size,
                              hipStream_t stream) {
    const float* x   = (const float*)d_in[0];
    const float* W1  = (const float*)d_in[1];
    const float* b1  = (const float*)d_in[2];
    const float* g1  = (const float*)d_in[3];
    const float* bt1 = (const float*)d_in[4];
    const float* W2  = (const float*)d_in[5];
    const float* b2  = (const float*)d_in[6];
    const float* g2  = (const float*)d_in[7];
    const float* bt2 = (const float*)d_in[8];
    const float* W3  = (const float*)d_in[9];
    const float* b3  = (const float*)d_in[10];
    const int*  edge = (const int*)d_in[11];

    int n = in_sizes[0] / 64;            // 50000 (< 65536: src fits 16 bits)
    int E = in_sizes[11] / 2;
    const int* src = edge;
    const int* dst = edge + E;
    float* out = (float*)d_out;
    int nblk  = (n + 255) / 256;
    int NW    = (n + 8191) >> 13;        // windows (7)
    int NBUCK = (n + 31) >> 5;           // final buckets (1563)
    int cap1  = CSLOT * 4096;            // 278528 per window
    int cap2  = 1280;                    // per bucket (expected ~1024)

    // ---- workspace ----
    char* p = (char*)d_ws;
    double* stats = (double*)p;            p += 256 * sizeof(double);
    float* dinv   = (float*)p;             p += ((n + 63) & ~63) * sizeof(float);
    int* degi     = (int*)p;               p += ((n + 63) & ~63) * sizeof(int);
    int* off      = (int*)p;               p += ((n + 64) & ~63) * sizeof(int);
    int* part     = (int*)p;               p += 256 * sizeof(int);
    int* gcur1    = (int*)p;               p += 64 * sizeof(int);
    int* gcur2    = (int*)p;               p += ((NBUCK + 63) & ~63) * sizeof(int);
    int* csr      = (int*)p;               p += (size_t)E * sizeof(int);
    unsigned* A   = (unsigned*)p;          p += (size_t)n * 32 * sizeof(unsigned); // bf16 T (6.4MB)
    float* B      = (float*)p;             p += (size_t)n * 64 * sizeof(float);    // Y (12.8MB)
    float* hs3    = (float*)p;             /* n floats */
    // staging aliases A+B (dead during CSR build): st2 8MB, st1 7.8MB
    unsigned* st2 = (unsigned*)A;
    unsigned* st1 = (unsigned*)((char*)A + (size_t)NBUCK * cap2 * sizeof(unsigned));

    hipMemsetAsync(gcur1, 0, (64 + ((NBUCK + 63) & ~63)) * sizeof(int), stream);
    hipMemsetAsync(stats, 0, 256 * sizeof(double), stream);

    // CSR build (binned, block-exclusive final writes)
    binA<<<(E + 2047) / 2048, 256, 0, stream>>>(src, dst, gcur1, st1, E, cap1);
    binB<<<NW * CSLOT, 256, 0, stream>>>(gcur1, st1, gcur2, st2, cap1, cap2);
    bucket_degB<<<NBUCK, 256, 0, stream>>>(gcur2, st2, degi, n, cap2);
    scan_part<<<nblk, 256, 0, stream>>>(degi, part, n);
    scan_root<<<1, 256, 0, stream>>>(part, nblk);
    scan_write<<<nblk, 256, 0, stream>>>(degi, part, off, dinv, n);
    fillC<<<NBUCK, 256, 0, stream>>>(gcur2, st2, off, csr, n, cap2);

    // layer 1: T1 = bf16(x*dinv) ; y1 = dinv*(gather-sum T1)@W1 + b1
    prescale<<<1024, 256, 0, stream>>>(x, dinv, A, n);
    agg_mm<<<2048, 256, 0, stream>>>((const uint4*)A, csr, off, dinv, W1, b1,
                                     stats, B, n);
    // layer 2: T2 = bf16(relu(BN1(y1))*dinv) ; y2 = dinv*(gather-sum T2)@W2 + b2
    bnrelu_scale<<<1024, 256, 0, stream>>>(B, stats, g1, bt1, dinv, A, n);
    agg_mm<<<2048, 256, 0, stream>>>((const uint4*)A, csr, off, dinv, W2, b2,
                                     stats + 128, B, n);
    // layer 3 (f32 path, tiny)
    head_w3<<<2048, 256, 0, stream>>>(B, stats + 128, g2, bt2, W3, dinv, hs3, n);
    agg1<<<2048, 256, 0, stream>>>(hs3, csr, off, dinv, b3, out, n);
}

// Round 16
// 372.865 us; speedup vs baseline: 1.0332x; 1.0332x over previous
//
#include <hip/hip_runtime.h>
#include <hip/hip_bf16.h>

// GCN, CSR-gather (u32 csr), bf16 T-tables, fused agg+matvec.
//   T = bf16(f(X)*dinv) ; y[d] = dinv[d]*(sum_{s in N(d)} T[s] + T[d])@W + b
// agg_mm: one node/wave, 4 edge-slots x 16 lanes (uint2 = 4 bf16/lane),
//   depth-8 gather with UNIFORM batch loop (2 fixed halves) -- __shfl must run
//   with all 64 lanes active; only loads/accumulates are predicated (r15 bug:
//   divergent batch loop made shfl read inactive lanes for 33<=deg<=63).

__device__ __forceinline__ unsigned f2bf(float f) {   // round-to-nearest-even
    unsigned u = __float_as_uint(f);
    return (u + 0x7FFFu + ((u >> 16) & 1u)) >> 16;
}
__device__ __forceinline__ float bflo(unsigned w) { return __uint_as_float(w << 16); }
__device__ __forceinline__ float bfhi(unsigned w) { return __uint_as_float(w & 0xFFFF0000u); }

// ---- degree count ----
__global__ void deg_count(const int* __restrict__ dst, int* __restrict__ degi, int E) {
    int tid = blockIdx.x * blockDim.x + threadIdx.x;
    int stride = gridDim.x * blockDim.x;
    for (int e = tid; e < E; e += stride) atomicAdd(&degi[dst[e]], 1);
}

__global__ void scan_part(const int* __restrict__ degi, int* __restrict__ part, int n) {
    __shared__ int ls[256];
    int i = blockIdx.x * 256 + threadIdx.x;
    ls[threadIdx.x] = (i < n) ? degi[i] : 0;
    __syncthreads();
    for (int o = 128; o > 0; o >>= 1) {
        if (threadIdx.x < o) ls[threadIdx.x] += ls[threadIdx.x + o];
        __syncthreads();
    }
    if (threadIdx.x == 0) part[blockIdx.x] = ls[0];
}

__global__ void scan_root(int* __restrict__ part, int nblk) {   // nblk <= 256
    __shared__ int ls[256];
    int t = threadIdx.x;
    int v = (t < nblk) ? part[t] : 0;
    ls[t] = v;
    __syncthreads();
    for (int o = 1; o < 256; o <<= 1) {
        int u = (t >= o) ? ls[t - o] : 0;
        __syncthreads();
        ls[t] += u;
        __syncthreads();
    }
    if (t < nblk) part[t] = ls[t] - v;   // exclusive
}

__global__ void scan_write(const int* __restrict__ degi, const int* __restrict__ part,
                           int* __restrict__ off, int* __restrict__ cur,
                           float* __restrict__ dinv, int n) {
    __shared__ int ls[256];
    int t = threadIdx.x, i = blockIdx.x * 256 + t;
    int d = (i < n) ? degi[i] : 0;
    ls[t] = d;
    __syncthreads();
    for (int o = 1; o < 256; o <<= 1) {
        int u = (t >= o) ? ls[t - o] : 0;
        __syncthreads();
        ls[t] += u;
        __syncthreads();
    }
    if (i < n) {
        int o0 = part[blockIdx.x] + ls[t] - d;
        off[i] = o0;
        cur[i] = o0;
        dinv[i] = rsqrtf((float)d + 1.0f);   // +1 self loop
        if (i == n - 1) off[n] = o0 + d;
    }
}

// ---- windowed CSR fill ----
__global__ void csr_fill_x(const int* __restrict__ src, const int* __restrict__ dst,
                           int* __restrict__ cur, int* __restrict__ csr, int E, int n) {
    int w = blockIdx.x & 7;
    int lo = (int)(((long long)n * w) >> 3);
    int hi = (int)(((long long)n * (w + 1)) >> 3);
    int tid = (blockIdx.x >> 3) * blockDim.x + threadIdx.x;
    int stride = (gridDim.x >> 3) * blockDim.x;
    for (int e = tid; e < E; e += stride) {
        int d = dst[e];
        if (d >= lo && d < hi) {
            int p = atomicAdd(&cur[d], 1);
            csr[p] = src[e];
        }
    }
}

// ---- T1 = bf16(x * dinv) ----
__global__ void prescale(const float* __restrict__ x, const float* __restrict__ dinv,
                         unsigned* __restrict__ T, int n) {
    int tid = blockIdx.x * blockDim.x + threadIdx.x;
    int stride = gridDim.x * blockDim.x;
    int total = n * 32;   // u32 count (2 features each)
    const float2* x2 = (const float2*)x;
    for (int i = tid; i < total; i += stride) {
        float2 v = x2[i];
        float dv = dinv[i >> 5];
        T[i] = f2bf(v.x * dv) | (f2bf(v.y * dv) << 16);
    }
}

// ---- T2 = bf16(relu(BN(y)) * dinv) ----
__global__ void bnrelu_scale(const float* __restrict__ Y, const double* __restrict__ stats,
                             const float* __restrict__ g, const float* __restrict__ bt,
                             const float* __restrict__ dinv, unsigned* __restrict__ T, int n) {
    int jj = threadIdx.x & 31;            // u32 index within row
    int f0 = jj * 2, f1 = jj * 2 + 1;
    double m0 = stats[f0] / n, m1 = stats[f1] / n;
    double v0 = stats[64 + f0] / n - m0 * m0, v1 = stats[64 + f1] / n - m1 * m1;
    float sc0 = (float)(1.0 / sqrt(v0 + 1e-5)) * g[f0];
    float sc1 = (float)(1.0 / sqrt(v1 + 1e-5)) * g[f1];
    float sh0 = bt[f0] - (float)m0 * sc0;
    float sh1 = bt[f1] - (float)m1 * sc1;
    const float2* Y2 = (const float2*)Y;
    int tid = blockIdx.x * blockDim.x + threadIdx.x;
    int stride = gridDim.x * blockDim.x;   // multiple of 32
    for (int i = tid; i < n * 32; i += stride) {
        float2 y = Y2[i];
        float dv = dinv[i >> 5];
        float a = fmaxf(y.x * sc0 + sh0, 0.f) * dv;
        float b = fmaxf(y.y * sc1 + sh1, 0.f) * dv;
        T[i] = f2bf(a) | (f2bf(b) << 16);
    }
}

// ---- fused layer: depth-8 bf16 gather-sum -> @W -> *dinv + b -> stats ----
__global__ __launch_bounds__(256) void agg_mm(
        const uint2* __restrict__ Tb, const int* __restrict__ csr,
        const int* __restrict__ off, const float* __restrict__ dinv,
        const float* __restrict__ W, const float* __restrict__ bias,
        double* __restrict__ stats_out, float* __restrict__ Y, int n) {
    __shared__ float Wl[64 * 64];
    __shared__ double ls[256], lq[256];
    for (int t = threadIdx.x; t < 64 * 64; t += blockDim.x) Wl[t] = W[t];

    int lane = threadIdx.x & 63;
    int slot = lane >> 4;      // 4 edge slots
    int fc   = lane & 15;      // features 4*fc .. 4*fc+3  (one uint2 = 4 bf16)
    float bv = bias[lane];
    __syncthreads();

    int wave  = (blockIdx.x * blockDim.x + threadIdx.x) >> 6;
    int nwave = (gridDim.x * blockDim.x) >> 6;
    double s = 0.0, sq = 0.0;

    for (int i = wave; i < n; i += nwave) {
        int beg = off[i], end = off[i + 1];
        int cnt = end - beg;
        // one wave-load grabs up to 64 edge indices
        int idx = (lane < cnt) ? csr[beg + lane] : 0;

        float4 a = {0.f, 0.f, 0.f, 0.f};
        if (slot == 0) {                       // self term in slot 0 only
            uint2 r = Tb[(size_t)i * 16 + fc];
            a.x = bflo(r.x); a.y = bfhi(r.x);
            a.z = bflo(r.y); a.w = bfhi(r.y);
        }

        int nb = min(cnt, 64);
        // UNIFORM structure: both halves executed by ALL lanes (shfl needs the
        // full wave active); only loads/accumulates are predicated.
        #pragma unroll
        for (int half = 0; half < 2; ++half) {
            int o0 = slot + half * 32;
            uint2 r[8];
            #pragma unroll
            for (int t = 0; t < 8; ++t) {
                int oo = o0 + 4 * t;
                int row = __shfl(idx, oo, 64);     // all 64 lanes participate
                if (oo < nb) r[t] = Tb[(size_t)row * 16 + fc];
            }
            #pragma unroll
            for (int t = 0; t < 8; ++t) {
                if (o0 + 4 * t < nb) {
                    a.x += bflo(r[t].x); a.y += bfhi(r[t].x);
                    a.z += bflo(r[t].y); a.w += bfhi(r[t].y);
                }
            }
        }
        // rare tail (deg > 64)
        for (int c = beg + 64 + slot; c < end; c += 4) {
            int sr = csr[c];
            uint2 rr = Tb[(size_t)sr * 16 + fc];
            a.x += bflo(rr.x); a.y += bfhi(rr.x);
            a.z += bflo(rr.y); a.w += bfhi(rr.y);
        }

        // reduce across the 4 slots (lane bits 4,5)
        #pragma unroll
        for (int m = 16; m <= 32; m <<= 1) {
            a.x += __shfl_xor(a.x, m, 64); a.y += __shfl_xor(a.y, m, 64);
            a.z += __shfl_xor(a.z, m, 64); a.w += __shfl_xor(a.w, m, 64);
        }

        // matvec: feature k = component (k&3) of lane (k>>2); out col = lane
        float acc = 0.f;
        #pragma unroll
        for (int k = 0; k < 64; ++k) {
            const int c = k & 3, sl = k >> 2;
            float comp = c == 0 ? a.x : c == 1 ? a.y : c == 2 ? a.z : a.w;
            acc = fmaf(__shfl(comp, sl, 64), Wl[k * 64 + lane], acc);
        }
        float dv = dinv[i];
        float yv = dv * acc + bv;
        Y[(size_t)i * 64 + lane] = yv;
        s += (double)yv; sq += (double)yv * (double)yv;
    }

    ls[threadIdx.x] = s; lq[threadIdx.x] = sq;
    __syncthreads();
    if (threadIdx.x < 64) {
        double ts = ls[threadIdx.x] + ls[threadIdx.x + 64] + ls[threadIdx.x + 128] + ls[threadIdx.x + 192];
        double tq = lq[threadIdx.x] + lq[threadIdx.x + 64] + lq[threadIdx.x + 128] + lq[threadIdx.x + 192];
        atomicAdd(&stats_out[threadIdx.x], ts);
        atomicAdd(&stats_out[64 + threadIdx.x], tq);
    }
}

// ---- head: hs3[row] = (relu(BN(y2[row])) . W3) * dinv[row] ----
__global__ void head_w3(const float* __restrict__ Y, const double* __restrict__ stats,
                        const float* __restrict__ g, const float* __restrict__ bt,
                        const float* __restrict__ W3, const float* __restrict__ dinv,
                        float* __restrict__ hs3, int n) {
    int lane = threadIdx.x & 63;
    double mean = stats[lane] / n;
    double var  = stats[64 + lane] / n - mean * mean;
    float scale = (float)(1.0 / sqrt(var + 1e-5)) * g[lane];
    float shift = bt[lane] - (float)mean * scale;
    float w = W3[lane];
    int wave  = (blockIdx.x * blockDim.x + threadIdx.x) >> 6;
    int nwave = (gridDim.x * blockDim.x) >> 6;
    for (int row = wave; row < n; row += nwave) {
        float v = fmaxf(Y[(size_t)row * 64 + lane] * scale + shift, 0.f) * w;
        #pragma unroll
        for (int o = 32; o > 0; o >>= 1) v += __shfl_down(v, o, 64);
        if (lane == 0) hs3[row] = v * dinv[row];
    }
}

// ---- layer-3 aggregation: wave per node, lane-parallel edge gather ----
__global__ void agg1(const float* __restrict__ hs3, const int* __restrict__ csr,
                     const int* __restrict__ off, const float* __restrict__ dinv,
                     const float* __restrict__ b3, float* __restrict__ out, int n) {
    float b = b3[0];
    int lane  = threadIdx.x & 63;
    int wave  = (blockIdx.x * blockDim.x + threadIdx.x) >> 6;
    int nwave = (gridDim.x * blockDim.x) >> 6;
    for (int i = wave; i < n; i += nwave) {
        int beg = off[i], end = off[i + 1];
        float acc = 0.f;
        for (int e = beg + lane; e < end; e += 64) acc += hs3[csr[e]];
        #pragma unroll
        for (int o = 32; o > 0; o >>= 1) acc += __shfl_down(acc, o, 64);
        if (lane == 0) out[i] = dinv[i] * (acc + hs3[i]) + b;
    }
}

extern "C" void kernel_launch(void* const* d_in, const int* in_sizes, int n_in,
                              void* d_out, int out_size, void* d_ws, size_t ws_size,
                              hipStream_t stream) {
    const float* x   = (const float*)d_in[0];
    const float* W1  = (const float*)d_in[1];
    const float* b1  = (const float*)d_in[2];
    const float* g1  = (const float*)d_in[3];
    const float* bt1 = (const float*)d_in[4];
    const float* W2  = (const float*)d_in[5];
    const float* b2  = (const float*)d_in[6];
    const float* g2  = (const float*)d_in[7];
    const float* bt2 = (const float*)d_in[8];
    const float* W3  = (const float*)d_in[9];
    const float* b3  = (const float*)d_in[10];
    const int*  edge = (const int*)d_in[11];

    int n = in_sizes[0] / 64;
    int E = in_sizes[11] / 2;
    const int* src = edge;
    const int* dst = edge + E;
    float* out = (float*)d_out;
    int nblk = (n + 255) / 256;

    // ---- workspace ----
    char* p = (char*)d_ws;
    double* stats = (double*)p;            p += 256 * sizeof(double);  // L1:0..127, L2:128..255
    float* dinv   = (float*)p;             p += ((n + 63) & ~63) * sizeof(float);
    int* degi     = (int*)p;               p += ((n + 63) & ~63) * sizeof(int);
    int* off      = (int*)p;               p += ((n + 64) & ~63) * sizeof(int);
    int* cur      = (int*)p;               p += ((n + 63) & ~63) * sizeof(int);
    int* part     = (int*)p;               p += 256 * sizeof(int);
    int* csr      = (int*)p;               p += (size_t)E * sizeof(int);
    unsigned* A   = (unsigned*)p;          p += (size_t)n * 32 * sizeof(unsigned); // bf16 T (6.4MB)
    float* B      = (float*)p;             p += (size_t)n * 64 * sizeof(float);    // Y (12.8MB)
    float* hs3    = (float*)p;             /* n floats */

    hipMemsetAsync(degi, 0, n * sizeof(int), stream);
    hipMemsetAsync(stats, 0, 256 * sizeof(double), stream);

    // CSR build
    deg_count<<<2048, 256, 0, stream>>>(dst, degi, E);
    scan_part<<<nblk, 256, 0, stream>>>(degi, part, n);
    scan_root<<<1, 256, 0, stream>>>(part, nblk);
    scan_write<<<nblk, 256, 0, stream>>>(degi, part, off, cur, dinv, n);
    csr_fill_x<<<2048, 256, 0, stream>>>(src, dst, cur, csr, E, n);

    // layer 1: T1 = bf16(x*dinv) ; y1 = dinv*(gather-sum T1)@W1 + b1
    prescale<<<1024, 256, 0, stream>>>(x, dinv, A, n);
    agg_mm<<<2048, 256, 0, stream>>>((const uint2*)A, csr, off, dinv, W1, b1,
                                     stats, B, n);
    // layer 2: T2 = bf16(relu(BN1(y1))*dinv) ; y2 = dinv*(gather-sum T2)@W2 + b2
    bnrelu_scale<<<1024, 256, 0, stream>>>(B, stats, g1, bt1, dinv, A, n);
    agg_mm<<<2048, 256, 0, stream>>>((const uint2*)A, csr, off, dinv, W2, b2,
                                     stats + 128, B, n);
    // layer 3 (f32 path, tiny)
    head_w3<<<2048, 256, 0, stream>>>(B, stats + 128, g2, bt2, W3, dinv, hs3, n);
    agg1<<<2048, 256, 0, stream>>>(hs3, csr, off, dinv, b3, out, n);
}

// Round 17
// 370.261 us; speedup vs baseline: 1.0404x; 1.0070x over previous
//
#include <hip/hip_runtime.h>
#include <hip/hip_bf16.h>

// GCN, CSR-gather (u32), bf16 T-tables, fused agg+matvec (round-11 structure:
// 8 edge-slots x uint4/lane, unroll-2 -- proven 92us, VGPR 64).
// This round: NON-TEMPORAL hints on all streaming traffic so the L2 keeps
// (a) in-progress csr lines during fill (write-combining) and (b) the
// randomly-gathered T table during agg_mm.

__device__ __forceinline__ unsigned f2bf(float f) {   // round-to-nearest-even
    unsigned u = __float_as_uint(f);
    return (u + 0x7FFFu + ((u >> 16) & 1u)) >> 16;
}
__device__ __forceinline__ float bflo(unsigned w) { return __uint_as_float(w << 16); }
__device__ __forceinline__ float bfhi(unsigned w) { return __uint_as_float(w & 0xFFFF0000u); }

// ---- degree count ----
__global__ void deg_count(const int* __restrict__ dst, int* __restrict__ degi, int E) {
    int tid = blockIdx.x * blockDim.x + threadIdx.x;
    int stride = gridDim.x * blockDim.x;
    for (int e = tid; e < E; e += stride) {
        int d = __builtin_nontemporal_load(&dst[e]);
        atomicAdd(&degi[d], 1);
    }
}

__global__ void scan_part(const int* __restrict__ degi, int* __restrict__ part, int n) {
    __shared__ int ls[256];
    int i = blockIdx.x * 256 + threadIdx.x;
    ls[threadIdx.x] = (i < n) ? degi[i] : 0;
    __syncthreads();
    for (int o = 128; o > 0; o >>= 1) {
        if (threadIdx.x < o) ls[threadIdx.x] += ls[threadIdx.x + o];
        __syncthreads();
    }
    if (threadIdx.x == 0) part[blockIdx.x] = ls[0];
}

__global__ void scan_root(int* __restrict__ part, int nblk) {   // nblk <= 256
    __shared__ int ls[256];
    int t = threadIdx.x;
    int v = (t < nblk) ? part[t] : 0;
    ls[t] = v;
    __syncthreads();
    for (int o = 1; o < 256; o <<= 1) {
        int u = (t >= o) ? ls[t - o] : 0;
        __syncthreads();
        ls[t] += u;
        __syncthreads();
    }
    if (t < nblk) part[t] = ls[t] - v;   // exclusive
}

__global__ void scan_write(const int* __restrict__ degi, const int* __restrict__ part,
                           int* __restrict__ off, int* __restrict__ cur,
                           float* __restrict__ dinv, int n) {
    __shared__ int ls[256];
    int t = threadIdx.x, i = blockIdx.x * 256 + t;
    int d = (i < n) ? degi[i] : 0;
    ls[t] = d;
    __syncthreads();
    for (int o = 1; o < 256; o <<= 1) {
        int u = (t >= o) ? ls[t - o] : 0;
        __syncthreads();
        ls[t] += u;
        __syncthreads();
    }
    if (i < n) {
        int o0 = part[blockIdx.x] + ls[t] - d;
        off[i] = o0;
        cur[i] = o0;
        dinv[i] = rsqrtf((float)d + 1.0f);   // +1 self loop
        if (i == n - 1) off[n] = o0 + d;
    }
}

// ---- windowed CSR fill; src/dst streamed NON-TEMPORALLY so the in-progress
// csr lines stay resident in L2 and coalesce to full-line writebacks ----
__global__ void csr_fill_x(const int* __restrict__ src, const int* __restrict__ dst,
                           int* __restrict__ cur, int* __restrict__ csr, int E, int n) {
    int w = blockIdx.x & 7;
    int lo = (int)(((long long)n * w) >> 3);
    int hi = (int)(((long long)n * (w + 1)) >> 3);
    int tid = (blockIdx.x >> 3) * blockDim.x + threadIdx.x;
    int stride = (gridDim.x >> 3) * blockDim.x;
    for (int e = tid; e < E; e += stride) {
        int d = __builtin_nontemporal_load(&dst[e]);
        if (d >= lo && d < hi) {
            int s = __builtin_nontemporal_load(&src[e]);
            int p = atomicAdd(&cur[d], 1);
            csr[p] = s;                        // cached store: let lines fill
        }
    }
}

// ---- T1 = bf16(x * dinv); nt-store T (push to L3 for cross-XCD readers) ----
__global__ void prescale(const float* __restrict__ x, const float* __restrict__ dinv,
                         unsigned* __restrict__ T, int n) {
    int tid = blockIdx.x * blockDim.x + threadIdx.x;
    int stride = gridDim.x * blockDim.x;
    int total = n * 32;   // u32 count (2 features each)
    const float2* x2 = (const float2*)x;
    for (int i = tid; i < total; i += stride) {
        float2 v = x2[i];
        float dv = dinv[i >> 5];
        __builtin_nontemporal_store(f2bf(v.x * dv) | (f2bf(v.y * dv) << 16), &T[i]);
    }
}

// ---- T2 = bf16(relu(BN(y)) * dinv); nt-load Y, nt-store T ----
__global__ void bnrelu_scale(const float* __restrict__ Y, const double* __restrict__ stats,
                             const float* __restrict__ g, const float* __restrict__ bt,
                             const float* __restrict__ dinv, unsigned* __restrict__ T, int n) {
    int jj = threadIdx.x & 31;            // u32 index within row
    int f0 = jj * 2, f1 = jj * 2 + 1;
    double m0 = stats[f0] / n, m1 = stats[f1] / n;
    double v0 = stats[64 + f0] / n - m0 * m0, v1 = stats[64 + f1] / n - m1 * m1;
    float sc0 = (float)(1.0 / sqrt(v0 + 1e-5)) * g[f0];
    float sc1 = (float)(1.0 / sqrt(v1 + 1e-5)) * g[f1];
    float sh0 = bt[f0] - (float)m0 * sc0;
    float sh1 = bt[f1] - (float)m1 * sc1;
    int tid = blockIdx.x * blockDim.x + threadIdx.x;
    int stride = gridDim.x * blockDim.x;   // multiple of 32
    for (int i = tid; i < n * 32; i += stride) {
        float yx = __builtin_nontemporal_load(&Y[2 * i]);
        float yy = __builtin_nontemporal_load(&Y[2 * i + 1]);
        float dv = dinv[i >> 5];
        float a = fmaxf(yx * sc0 + sh0, 0.f) * dv;
        float b = fmaxf(yy * sc1 + sh1, 0.f) * dv;
        __builtin_nontemporal_store(f2bf(a) | (f2bf(b) << 16), &T[i]);
    }
}

// ---- fused layer: bf16 gather-sum (f32 accum) -> @W -> *dinv + b -> stats ----
__global__ __launch_bounds__(256) void agg_mm(
        const uint4* __restrict__ Tb, const int* __restrict__ csr,
        const int* __restrict__ off, const float* __restrict__ dinv,
        const float* __restrict__ W, const float* __restrict__ bias,
        double* __restrict__ stats_out, float* __restrict__ Y, int n) {
    __shared__ float Wl[64 * 64];
    __shared__ double ls[256], lq[256];
    for (int t = threadIdx.x; t < 64 * 64; t += blockDim.x) Wl[t] = W[t];

    int lane = threadIdx.x & 63;
    int slot = lane >> 3;      // 8 edge slots
    int fl   = lane & 7;       // features 8*fl .. 8*fl+7  (one uint4 = 8 bf16)
    float bv = bias[lane];
    __syncthreads();

    int wave  = (blockIdx.x * blockDim.x + threadIdx.x) >> 6;
    int nwave = (gridDim.x * blockDim.x) >> 6;
    double s = 0.0, sq = 0.0;

    for (int i = wave; i < n; i += nwave) {
        int beg = off[i], end = off[i + 1];
        float dv = dinv[i];

        float4 al = {0,0,0,0}, ah = {0,0,0,0};
        if (slot == 0) {                       // self term in slot 0 only
            uint4 r = Tb[(size_t)i * 8 + fl];
            al.x = bflo(r.x); al.y = bfhi(r.x);
            al.z = bflo(r.y); al.w = bfhi(r.y);
            ah.x = bflo(r.z); ah.y = bfhi(r.z);
            ah.z = bflo(r.w); ah.w = bfhi(r.w);
        }

        #pragma unroll 2
        for (int c = beg + slot; c < end; c += 8) {
            int sr = csr[c];                    // 8-lane broadcast per slot
            uint4 r = Tb[(size_t)sr * 8 + fl];
            al.x += bflo(r.x); al.y += bfhi(r.x);
            al.z += bflo(r.y); al.w += bfhi(r.y);
            ah.x += bflo(r.z); ah.y += bfhi(r.z);
            ah.z += bflo(r.w); ah.w += bfhi(r.w);
        }

        // reduce across the 8 slots (lane bits 3,4,5)
        #pragma unroll
        for (int m = 8; m <= 32; m <<= 1) {
            al.x += __shfl_xor(al.x, m, 64); al.y += __shfl_xor(al.y, m, 64);
            al.z += __shfl_xor(al.z, m, 64); al.w += __shfl_xor(al.w, m, 64);
            ah.x += __shfl_xor(ah.x, m, 64); ah.y += __shfl_xor(ah.y, m, 64);
            ah.z += __shfl_xor(ah.z, m, 64); ah.w += __shfl_xor(ah.w, m, 64);
        }

        // matvec: feature k owned by lane (k>>3), component (k&7)
        float acc = 0.f;
        #pragma unroll
        for (int k = 0; k < 64; ++k) {
            const int c = k & 7, sl = k >> 3;
            float comp = c == 0 ? al.x : c == 1 ? al.y : c == 2 ? al.z : c == 3 ? al.w
                       : c == 4 ? ah.x : c == 5 ? ah.y : c == 6 ? ah.z : ah.w;
            acc = fmaf(__shfl(comp, sl, 64), Wl[k * 64 + lane], acc);
        }
        float yv = dv * acc + bv;
        __builtin_nontemporal_store(yv, &Y[(size_t)i * 64 + lane]);  // streaming out
        s += (double)yv; sq += (double)yv * (double)yv;
    }

    ls[threadIdx.x] = s; lq[threadIdx.x] = sq;
    __syncthreads();
    if (threadIdx.x < 64) {
        double ts = ls[threadIdx.x] + ls[threadIdx.x + 64] + ls[threadIdx.x + 128] + ls[threadIdx.x + 192];
        double tq = lq[threadIdx.x] + lq[threadIdx.x + 64] + lq[threadIdx.x + 128] + lq[threadIdx.x + 192];
        atomicAdd(&stats_out[threadIdx.x], ts);
        atomicAdd(&stats_out[64 + threadIdx.x], tq);
    }
}

// ---- head: hs3[row] = (relu(BN(y2[row])) . W3) * dinv[row] ----
__global__ void head_w3(const float* __restrict__ Y, const double* __restrict__ stats,
                        const float* __restrict__ g, const float* __restrict__ bt,
                        const float* __restrict__ W3, const float* __restrict__ dinv,
                        float* __restrict__ hs3, int n) {
    int lane = threadIdx.x & 63;
    double mean = stats[lane] / n;
    double var  = stats[64 + lane] / n - mean * mean;
    float scale = (float)(1.0 / sqrt(var + 1e-5)) * g[lane];
    float shift = bt[lane] - (float)mean * scale;
    float w = W3[lane];
    int wave  = (blockIdx.x * blockDim.x + threadIdx.x) >> 6;
    int nwave = (gridDim.x * blockDim.x) >> 6;
    for (int row = wave; row < n; row += nwave) {
        float yv = __builtin_nontemporal_load(&Y[(size_t)row * 64 + lane]);
        float v = fmaxf(yv * scale + shift, 0.f) * w;
        #pragma unroll
        for (int o = 32; o > 0; o >>= 1) v += __shfl_down(v, o, 64);
        if (lane == 0) hs3[row] = v * dinv[row];
    }
}

// ---- layer-3 aggregation: wave per node, lane-parallel edge gather ----
__global__ void agg1(const float* __restrict__ hs3, const int* __restrict__ csr,
                     const int* __restrict__ off, const float* __restrict__ dinv,
                     const float* __restrict__ b3, float* __restrict__ out, int n) {
    float b = b3[0];
    int lane  = threadIdx.x & 63;
    int wave  = (blockIdx.x * blockDim.x + threadIdx.x) >> 6;
    int nwave = (gridDim.x * blockDim.x) >> 6;
    for (int i = wave; i < n; i += nwave) {
        int beg = off[i], end = off[i + 1];
        float acc = 0.f;
        for (int e = beg + lane; e < end; e += 64) acc += hs3[csr[e]];
        #pragma unroll
        for (int o = 32; o > 0; o >>= 1) acc += __shfl_down(acc, o, 64);
        if (lane == 0) out[i] = dinv[i] * (acc + hs3[i]) + b;
    }
}

extern "C" void kernel_launch(void* const* d_in, const int* in_sizes, int n_in,
                              void* d_out, int out_size, void* d_ws, size_t ws_size,
                              hipStream_t stream) {
    const float* x   = (const float*)d_in[0];
    const float* W1  = (const float*)d_in[1];
    const float* b1  = (const float*)d_in[2];
    const float* g1  = (const float*)d_in[3];
    const float* bt1 = (const float*)d_in[4];
    const float* W2  = (const float*)d_in[5];
    const float* b2  = (const float*)d_in[6];
    const float* g2  = (const float*)d_in[7];
    const float* bt2 = (const float*)d_in[8];
    const float* W3  = (const float*)d_in[9];
    const float* b3  = (const float*)d_in[10];
    const int*  edge = (const int*)d_in[11];

    int n = in_sizes[0] / 64;
    int E = in_sizes[11] / 2;
    const int* src = edge;
    const int* dst = edge + E;
    float* out = (float*)d_out;
    int nblk = (n + 255) / 256;

    // ---- workspace ----
    char* p = (char*)d_ws;
    double* stats = (double*)p;            p += 256 * sizeof(double);  // L1:0..127, L2:128..255
    float* dinv   = (float*)p;             p += ((n + 63) & ~63) * sizeof(float);
    int* degi     = (int*)p;               p += ((n + 63) & ~63) * sizeof(int);
    int* off      = (int*)p;               p += ((n + 64) & ~63) * sizeof(int);
    int* cur      = (int*)p;               p += ((n + 63) & ~63) * sizeof(int);
    int* part     = (int*)p;               p += 256 * sizeof(int);
    int* csr      = (int*)p;               p += (size_t)E * sizeof(int);
    unsigned* A   = (unsigned*)p;          p += (size_t)n * 32 * sizeof(unsigned); // bf16 T (6.4MB)
    float* B      = (float*)p;             p += (size_t)n * 64 * sizeof(float);    // Y (12.8MB)
    float* hs3    = (float*)p;             /* n floats */

    hipMemsetAsync(degi, 0, n * sizeof(int), stream);
    hipMemsetAsync(stats, 0, 256 * sizeof(double), stream);

    // CSR build
    deg_count<<<2048, 256, 0, stream>>>(dst, degi, E);
    scan_part<<<nblk, 256, 0, stream>>>(degi, part, n);
    scan_root<<<1, 256, 0, stream>>>(part, nblk);
    scan_write<<<nblk, 256, 0, stream>>>(degi, part, off, cur, dinv, n);
    csr_fill_x<<<2048, 256, 0, stream>>>(src, dst, cur, csr, E, n);

    // layer 1: T1 = bf16(x*dinv) ; y1 = dinv*(gather-sum T1)@W1 + b1
    prescale<<<1024, 256, 0, stream>>>(x, dinv, A, n);
    agg_mm<<<2048, 256, 0, stream>>>((const uint4*)A, csr, off, dinv, W1, b1,
                                     stats, B, n);
    // layer 2: T2 = bf16(relu(BN1(y1))*dinv) ; y2 = dinv*(gather-sum T2)@W2 + b2
    bnrelu_scale<<<1024, 256, 0, stream>>>(B, stats, g1, bt1, dinv, A, n);
    agg_mm<<<2048, 256, 0, stream>>>((const uint4*)A, csr, off, dinv, W2, b2,
                                     stats + 128, B, n);
    // layer 3 (f32 path, tiny)
    head_w3<<<2048, 256, 0, stream>>>(B, stats + 128, g2, bt2, W3, dinv, hs3, n);
    agg1<<<2048, 256, 0, stream>>>(hs3, csr, off, dinv, b3, out, n);
}

// Round 18
// 339.598 us; speedup vs baseline: 1.1344x; 1.0903x over previous
//
#include <hip/hip_runtime.h>
#include <hip/hip_bf16.h>

// GCN, CSR-gather (u32), bf16 T-tables, fused agg+matvec.
//   T = bf16(f(X)*dinv) ; y[d] = dinv[d]*(sum_{s in N(d)} T[s] + T[d])@W + b
// agg_mm: r11 gather (8 slots x uint4/lane, unroll-2) + DS-FREE matvec:
//   W column in 64 VGPRs, S broadcast via v_readlane (VALU->SGPR) -- removes
//   128 of 152 per-node DS-pipe ops (the measured plateau was DS-bound).

__device__ __forceinline__ unsigned f2bf(float f) {   // round-to-nearest-even
    unsigned u = __float_as_uint(f);
    return (u + 0x7FFFu + ((u >> 16) & 1u)) >> 16;
}
__device__ __forceinline__ float bflo(unsigned w) { return __uint_as_float(w << 16); }
__device__ __forceinline__ float bfhi(unsigned w) { return __uint_as_float(w & 0xFFFF0000u); }

// ---- degree count ----
__global__ void deg_count(const int* __restrict__ dst, int* __restrict__ degi, int E) {
    int tid = blockIdx.x * blockDim.x + threadIdx.x;
    int stride = gridDim.x * blockDim.x;
    for (int e = tid; e < E; e += stride) atomicAdd(&degi[dst[e]], 1);
}

__global__ void scan_part(const int* __restrict__ degi, int* __restrict__ part, int n) {
    __shared__ int ls[256];
    int i = blockIdx.x * 256 + threadIdx.x;
    ls[threadIdx.x] = (i < n) ? degi[i] : 0;
    __syncthreads();
    for (int o = 128; o > 0; o >>= 1) {
        if (threadIdx.x < o) ls[threadIdx.x] += ls[threadIdx.x + o];
        __syncthreads();
    }
    if (threadIdx.x == 0) part[blockIdx.x] = ls[0];
}

__global__ void scan_root(int* __restrict__ part, int nblk) {   // nblk <= 256
    __shared__ int ls[256];
    int t = threadIdx.x;
    int v = (t < nblk) ? part[t] : 0;
    ls[t] = v;
    __syncthreads();
    for (int o = 1; o < 256; o <<= 1) {
        int u = (t >= o) ? ls[t - o] : 0;
        __syncthreads();
        ls[t] += u;
        __syncthreads();
    }
    if (t < nblk) part[t] = ls[t] - v;   // exclusive
}

__global__ void scan_write(const int* __restrict__ degi, const int* __restrict__ part,
                           int* __restrict__ off, int* __restrict__ cur,
                           float* __restrict__ dinv, int n) {
    __shared__ int ls[256];
    int t = threadIdx.x, i = blockIdx.x * 256 + t;
    int d = (i < n) ? degi[i] : 0;
    ls[t] = d;
    __syncthreads();
    for (int o = 1; o < 256; o <<= 1) {
        int u = (t >= o) ? ls[t - o] : 0;
        __syncthreads();
        ls[t] += u;
        __syncthreads();
    }
    if (i < n) {
        int o0 = part[blockIdx.x] + ls[t] - d;
        off[i] = o0;
        cur[i] = o0;
        dinv[i] = rsqrtf((float)d + 1.0f);   // +1 self loop
        if (i == n - 1) off[n] = o0 + d;
    }
}

// ---- windowed CSR fill ----
__global__ void csr_fill_x(const int* __restrict__ src, const int* __restrict__ dst,
                           int* __restrict__ cur, int* __restrict__ csr, int E, int n) {
    int w = blockIdx.x & 7;
    int lo = (int)(((long long)n * w) >> 3);
    int hi = (int)(((long long)n * (w + 1)) >> 3);
    int tid = (blockIdx.x >> 3) * blockDim.x + threadIdx.x;
    int stride = (gridDim.x >> 3) * blockDim.x;
    for (int e = tid; e < E; e += stride) {
        int d = dst[e];
        if (d >= lo && d < hi) {
            int p = atomicAdd(&cur[d], 1);
            csr[p] = src[e];
        }
    }
}

// ---- T1 = bf16(x * dinv) ----
__global__ void prescale(const float* __restrict__ x, const float* __restrict__ dinv,
                         unsigned* __restrict__ T, int n) {
    int tid = blockIdx.x * blockDim.x + threadIdx.x;
    int stride = gridDim.x * blockDim.x;
    int total = n * 32;   // u32 count (2 features each)
    const float2* x2 = (const float2*)x;
    for (int i = tid; i < total; i += stride) {
        float2 v = x2[i];
        float dv = dinv[i >> 5];
        T[i] = f2bf(v.x * dv) | (f2bf(v.y * dv) << 16);
    }
}

// ---- T2 = bf16(relu(BN(y)) * dinv) ----
__global__ void bnrelu_scale(const float* __restrict__ Y, const double* __restrict__ stats,
                             const float* __restrict__ g, const float* __restrict__ bt,
                             const float* __restrict__ dinv, unsigned* __restrict__ T, int n) {
    int jj = threadIdx.x & 31;            // u32 index within row
    int f0 = jj * 2, f1 = jj * 2 + 1;
    double m0 = stats[f0] / n, m1 = stats[f1] / n;
    double v0 = stats[64 + f0] / n - m0 * m0, v1 = stats[64 + f1] / n - m1 * m1;
    float sc0 = (float)(1.0 / sqrt(v0 + 1e-5)) * g[f0];
    float sc1 = (float)(1.0 / sqrt(v1 + 1e-5)) * g[f1];
    float sh0 = bt[f0] - (float)m0 * sc0;
    float sh1 = bt[f1] - (float)m1 * sc1;
    const float2* Y2 = (const float2*)Y;
    int tid = blockIdx.x * blockDim.x + threadIdx.x;
    int stride = gridDim.x * blockDim.x;   // multiple of 32
    for (int i = tid; i < n * 32; i += stride) {
        float2 y = Y2[i];
        float dv = dinv[i >> 5];
        float a = fmaxf(y.x * sc0 + sh0, 0.f) * dv;
        float b = fmaxf(y.y * sc1 + sh1, 0.f) * dv;
        T[i] = f2bf(a) | (f2bf(b) << 16);
    }
}

// ---- fused layer: bf16 gather-sum -> DS-free matvec -> *dinv + b -> stats ----
__global__ __launch_bounds__(256) void agg_mm(
        const uint4* __restrict__ Tb, const int* __restrict__ csr,
        const int* __restrict__ off, const float* __restrict__ dinv,
        const float* __restrict__ W, const float* __restrict__ bias,
        double* __restrict__ stats_out, float* __restrict__ Y, int n) {
    __shared__ double ls[256], lq[256];

    int lane = threadIdx.x & 63;
    int slot = lane >> 3;      // 8 edge slots
    int fl   = lane & 7;       // features 8*fl .. 8*fl+7  (one uint4 = 8 bf16)
    float bv = bias[lane];

    // W column 'lane' in registers (64 VGPR) -- no LDS in the hot loop
    float w[64];
    #pragma unroll
    for (int k = 0; k < 64; ++k) w[k] = W[k * 64 + lane];

    int wave  = (blockIdx.x * blockDim.x + threadIdx.x) >> 6;
    int nwave = (gridDim.x * blockDim.x) >> 6;
    double s = 0.0, sq = 0.0;

    for (int i = wave; i < n; i += nwave) {
        int beg = off[i], end = off[i + 1];
        float dv = dinv[i];

        float4 al = {0,0,0,0}, ah = {0,0,0,0};
        if (slot == 0) {                       // self term in slot 0 only
            uint4 r = Tb[(size_t)i * 8 + fl];
            al.x = bflo(r.x); al.y = bfhi(r.x);
            al.z = bflo(r.y); al.w = bfhi(r.y);
            ah.x = bflo(r.z); ah.y = bfhi(r.z);
            ah.z = bflo(r.w); ah.w = bfhi(r.w);
        }

        #pragma unroll 2
        for (int c = beg + slot; c < end; c += 8) {
            int sr = csr[c];                    // 8-lane broadcast per slot
            uint4 r = Tb[(size_t)sr * 8 + fl];
            al.x += bflo(r.x); al.y += bfhi(r.x);
            al.z += bflo(r.y); al.w += bfhi(r.y);
            ah.x += bflo(r.z); ah.y += bfhi(r.z);
            ah.z += bflo(r.w); ah.w += bfhi(r.w);
        }

        // reduce across the 8 slots (lane bits 3,4,5)
        #pragma unroll
        for (int m = 8; m <= 32; m <<= 1) {
            al.x += __shfl_xor(al.x, m, 64); al.y += __shfl_xor(al.y, m, 64);
            al.z += __shfl_xor(al.z, m, 64); al.w += __shfl_xor(al.w, m, 64);
            ah.x += __shfl_xor(ah.x, m, 64); ah.y += __shfl_xor(ah.y, m, 64);
            ah.z += __shfl_xor(ah.z, m, 64); ah.w += __shfl_xor(ah.w, m, 64);
        }
        // now every lane holds totals for features 8*fl..8*fl+7;
        // lanes 0..7 collectively hold all 64 features.

        // DS-free matvec: S[k] via v_readlane (uniform SGPR), w[k] in VGPR
        float acc = 0.f;
        #pragma unroll
        for (int k = 0; k < 64; ++k) {
            const int c = k & 7, sl = k >> 3;
            float comp = c == 0 ? al.x : c == 1 ? al.y : c == 2 ? al.z : c == 3 ? al.w
                       : c == 4 ? ah.x : c == 5 ? ah.y : c == 6 ? ah.z : ah.w;
            float sv = __uint_as_float(
                (unsigned)__builtin_amdgcn_readlane((int)__float_as_uint(comp), sl));
            acc = fmaf(sv, w[k], acc);
        }
        float yv = dv * acc + bv;
        Y[(size_t)i * 64 + lane] = yv;
        s += (double)yv; sq += (double)yv * (double)yv;
    }

    ls[threadIdx.x] = s; lq[threadIdx.x] = sq;
    __syncthreads();
    if (threadIdx.x < 64) {
        double ts = ls[threadIdx.x] + ls[threadIdx.x + 64] + ls[threadIdx.x + 128] + ls[threadIdx.x + 192];
        double tq = lq[threadIdx.x] + lq[threadIdx.x + 64] + lq[threadIdx.x + 128] + lq[threadIdx.x + 192];
        atomicAdd(&stats_out[threadIdx.x], ts);
        atomicAdd(&stats_out[64 + threadIdx.x], tq);
    }
}

// ---- head: hs3[row] = (relu(BN(y2[row])) . W3) * dinv[row] ----
__global__ void head_w3(const float* __restrict__ Y, const double* __restrict__ stats,
                        const float* __restrict__ g, const float* __restrict__ bt,
                        const float* __restrict__ W3, const float* __restrict__ dinv,
                        float* __restrict__ hs3, int n) {
    int lane = threadIdx.x & 63;
    double mean = stats[lane] / n;
    double var  = stats[64 + lane] / n - mean * mean;
    float scale = (float)(1.0 / sqrt(var + 1e-5)) * g[lane];
    float shift = bt[lane] - (float)mean * scale;
    float w = W3[lane];
    int wave  = (blockIdx.x * blockDim.x + threadIdx.x) >> 6;
    int nwave = (gridDim.x * blockDim.x) >> 6;
    for (int row = wave; row < n; row += nwave) {
        float v = fmaxf(Y[(size_t)row * 64 + lane] * scale + shift, 0.f) * w;
        #pragma unroll
        for (int o = 32; o > 0; o >>= 1) v += __shfl_down(v, o, 64);
        if (lane == 0) hs3[row] = v * dinv[row];
    }
}

// ---- layer-3 aggregation: wave per node, lane-parallel edge gather ----
__global__ void agg1(const float* __restrict__ hs3, const int* __restrict__ csr,
                     const int* __restrict__ off, const float* __restrict__ dinv,
                     const float* __restrict__ b3, float* __restrict__ out, int n) {
    float b = b3[0];
    int lane  = threadIdx.x & 63;
    int wave  = (blockIdx.x * blockDim.x + threadIdx.x) >> 6;
    int nwave = (gridDim.x * blockDim.x) >> 6;
    for (int i = wave; i < n; i += nwave) {
        int beg = off[i], end = off[i + 1];
        float acc = 0.f;
        for (int e = beg + lane; e < end; e += 64) acc += hs3[csr[e]];
        #pragma unroll
        for (int o = 32; o > 0; o >>= 1) acc += __shfl_down(acc, o, 64);
        if (lane == 0) out[i] = dinv[i] * (acc + hs3[i]) + b;
    }
}

extern "C" void kernel_launch(void* const* d_in, const int* in_sizes, int n_in,
                              void* d_out, int out_size, void* d_ws, size_t ws_size,
                              hipStream_t stream) {
    const float* x   = (const float*)d_in[0];
    const float* W1  = (const float*)d_in[1];
    const float* b1  = (const float*)d_in[2];
    const float* g1  = (const float*)d_in[3];
    const float* bt1 = (const float*)d_in[4];
    const float* W2  = (const float*)d_in[5];
    const float* b2  = (const float*)d_in[6];
    const float* g2  = (const float*)d_in[7];
    const float* bt2 = (const float*)d_in[8];
    const float* W3  = (const float*)d_in[9];
    const float* b3  = (const float*)d_in[10];
    const int*  edge = (const int*)d_in[11];

    int n = in_sizes[0] / 64;
    int E = in_sizes[11] / 2;
    const int* src = edge;
    const int* dst = edge + E;
    float* out = (float*)d_out;
    int nblk = (n + 255) / 256;

    // ---- workspace ----
    char* p = (char*)d_ws;
    double* stats = (double*)p;            p += 256 * sizeof(double);  // L1:0..127, L2:128..255
    float* dinv   = (float*)p;             p += ((n + 63) & ~63) * sizeof(float);
    int* degi     = (int*)p;               p += ((n + 63) & ~63) * sizeof(int);
    int* off      = (int*)p;               p += ((n + 64) & ~63) * sizeof(int);
    int* cur      = (int*)p;               p += ((n + 63) & ~63) * sizeof(int);
    int* part     = (int*)p;               p += 256 * sizeof(int);
    int* csr      = (int*)p;               p += (size_t)E * sizeof(int);
    unsigned* A   = (unsigned*)p;          p += (size_t)n * 32 * sizeof(unsigned); // bf16 T (6.4MB)
    float* B      = (float*)p;             p += (size_t)n * 64 * sizeof(float);    // Y (12.8MB)
    float* hs3    = (float*)p;             /* n floats */

    hipMemsetAsync(degi, 0, n * sizeof(int), stream);
    hipMemsetAsync(stats, 0, 256 * sizeof(double), stream);

    // CSR build
    deg_count<<<2048, 256, 0, stream>>>(dst, degi, E);
    scan_part<<<nblk, 256, 0, stream>>>(degi, part, n);
    scan_root<<<1, 256, 0, stream>>>(part, nblk);
    scan_write<<<nblk, 256, 0, stream>>>(degi, part, off, cur, dinv, n);
    csr_fill_x<<<2048, 256, 0, stream>>>(src, dst, cur, csr, E, n);

    // layer 1: T1 = bf16(x*dinv) ; y1 = dinv*(gather-sum T1)@W1 + b1
    prescale<<<1024, 256, 0, stream>>>(x, dinv, A, n);
    agg_mm<<<2048, 256, 0, stream>>>((const uint4*)A, csr, off, dinv, W1, b1,
                                     stats, B, n);
    // layer 2: T2 = bf16(relu(BN1(y1))*dinv) ; y2 = dinv*(gather-sum T2)@W2 + b2
    bnrelu_scale<<<1024, 256, 0, stream>>>(B, stats, g1, bt1, dinv, A, n);
    agg_mm<<<2048, 256, 0, stream>>>((const uint4*)A, csr, off, dinv, W2, b2,
                                     stats + 128, B, n);
    // layer 3 (f32 path, tiny)
    head_w3<<<2048, 256, 0, stream>>>(B, stats + 128, g2, bt2, W3, dinv, hs3, n);
    agg1<<<2048, 256, 0, stream>>>(hs3, csr, off, dinv, b3, out, n);
}